// Round 10
// baseline (121.279 us; speedup 1.0000x reference)
//
#include <hip/hip_runtime.h>

typedef unsigned short u16;
typedef __attribute__((ext_vector_type(8))) short short8;
typedef __attribute__((ext_vector_type(4))) float f32x4;

#define GL2LDS16(src, dst) __builtin_amdgcn_global_load_lds( \
    (const __attribute__((address_space(1))) void*)(src),    \
    (__attribute__((address_space(3))) void*)(dst), 16, 0, 0)

__device__ __forceinline__ u16 f2bf(float f) {
  union { float f; unsigned u; } v; v.f = f;
  unsigned r = v.u + 0x7fffu + ((v.u >> 16) & 1u);
  return (u16)(r >> 16);
}
__device__ __forceinline__ float bf2f(u16 h) {
  union { unsigned u; float f; } v; v.u = ((unsigned)h) << 16; return v.f;
}

// ---------------- gate-weight transpose: [K][J] fp32 -> [J][K] fp32 ----------------
__global__ void k_gateT(const float* __restrict__ gshW, const float* __restrict__ g1W,
                        const float* __restrict__ g2W, float* __restrict__ gshWT,
                        float* __restrict__ g1WT, float* __restrict__ g2WT) {
  int idx = blockIdx.x * 256 + threadIdx.x;
  if (idx < 12288) {
    int j = idx >> 10, k = idx & 1023;
    gshWT[j * 1024 + k] = gshW[k * 12 + j];
  } else if (idx < 16384) {
    int i2 = idx - 12288;
    int j = i2 >> 9, k = i2 & 511;
    g1WT[j * 512 + k] = g1W[k * 8 + j];
  } else if (idx < 20480) {
    int i2 = idx - 16384;
    int j = i2 >> 9, k = i2 & 511;
    g2WT[j * 512 + k] = g2W[k * 8 + j];
  }
}

// ------------- fused prep: gates (coalesced WT reads) + 6 weight transposes -------------
struct TD { const float* src; u16* dst; int lgTps; int lgNtx; int R; int C; int tileBase; };
struct PrepArgs {
  TD d[6];
  const float *xf, *x1, *x2;
  const float *gshWT, *gshB, *g1WT, *g1B, *g2WT, *g2B;
  u16 *xfb, *x1b, *x2b;
  float *gsh, *g1o, *g2o;
};

__global__ void k_prep(PrepArgs pa) {
  __shared__ float tile[32][33];
  const int bx = blockIdx.x;
  const int tid = threadIdx.x;
  if (bx >= 1024) {
    // ---- weight transpose+convert: fp32 [z][R][C] -> bf16 [z][C][R] ----
    const int xb = bx - 1024;
    int di = 0;
#pragma unroll
    for (int i = 1; i < 6; ++i)
      if (xb >= pa.d[i].tileBase) di = i;
    TD d = pa.d[di];
    const int local = xb - d.tileBase;
    const int slice = local >> d.lgTps;
    const int ti = local & ((1 << d.lgTps) - 1);
    const int tx = ti & ((1 << d.lgNtx) - 1);
    const int ty = ti >> d.lgNtx;
    const float* src = d.src + (size_t)slice * d.R * d.C;
    u16* dst = d.dst + (size_t)slice * d.R * d.C;
    const int c0 = tx * 32, r0 = ty * 32;
    const int ttx = tid & 31, tty = tid >> 5;
#pragma unroll
    for (int i = tty; i < 32; i += 8)
      tile[i][ttx] = src[(size_t)(r0 + i) * d.C + (c0 + ttx)];
    __syncthreads();
#pragma unroll
    for (int i = tty; i < 32; i += 8)
      dst[(size_t)(c0 + i) * d.R + (r0 + ttx)] = f2bf(tile[ttx][i]);
    return;
  }
  // ---- gates + bf16 casts: one wave per batch row, 4 rows/block, vectorized ----
  const int b = bx * 4 + (tid >> 6);
  const int lane = tid & 63;
  float s[12];
#pragma unroll
  for (int j = 0; j < 12; ++j) s[j] = 0.f;
  {
    const float4* x4 = (const float4*)(pa.xf + (size_t)b * 1024);
    uint2* xw = (uint2*)(pa.xfb + (size_t)b * 1024);
#pragma unroll
    for (int i = 0; i < 4; ++i) {
      const int kc = lane + 64 * i;  // float4 index, 4*kc = k
      float4 xv = x4[kc];
      uint2 pk;
      pk.x = (unsigned)f2bf(xv.x) | ((unsigned)f2bf(xv.y) << 16);
      pk.y = (unsigned)f2bf(xv.z) | ((unsigned)f2bf(xv.w) << 16);
      xw[kc] = pk;
#pragma unroll
      for (int j = 0; j < 12; ++j) {
        float4 wv = *(const float4*)(pa.gshWT + j * 1024 + 4 * kc);
        s[j] += xv.x * wv.x + xv.y * wv.y + xv.z * wv.z + xv.w * wv.w;
      }
    }
  }
  float u[8], w[8];
#pragma unroll
  for (int j = 0; j < 8; ++j) { u[j] = 0.f; w[j] = 0.f; }
  {
    const float4* x41 = (const float4*)(pa.x1 + (size_t)b * 512);
    const float4* x42 = (const float4*)(pa.x2 + (size_t)b * 512);
    uint2* xw1 = (uint2*)(pa.x1b + (size_t)b * 512);
    uint2* xw2 = (uint2*)(pa.x2b + (size_t)b * 512);
#pragma unroll
    for (int i = 0; i < 2; ++i) {
      const int kc = lane + 64 * i;
      float4 v1 = x41[kc], v2 = x42[kc];
      uint2 p1, p2;
      p1.x = (unsigned)f2bf(v1.x) | ((unsigned)f2bf(v1.y) << 16);
      p1.y = (unsigned)f2bf(v1.z) | ((unsigned)f2bf(v1.w) << 16);
      p2.x = (unsigned)f2bf(v2.x) | ((unsigned)f2bf(v2.y) << 16);
      p2.y = (unsigned)f2bf(v2.z) | ((unsigned)f2bf(v2.w) << 16);
      xw1[kc] = p1; xw2[kc] = p2;
#pragma unroll
      for (int j = 0; j < 8; ++j) {
        float4 w1v = *(const float4*)(pa.g1WT + j * 512 + 4 * kc);
        float4 w2v = *(const float4*)(pa.g2WT + j * 512 + 4 * kc);
        u[j] += v1.x * w1v.x + v1.y * w1v.y + v1.z * w1v.z + v1.w * w1v.w;
        w[j] += v2.x * w2v.x + v2.y * w2v.y + v2.z * w2v.z + v2.w * w2v.w;
      }
    }
  }
#pragma unroll
  for (int off = 32; off >= 1; off >>= 1) {
#pragma unroll
    for (int j = 0; j < 12; ++j) s[j] += __shfl_xor(s[j], off, 64);
#pragma unroll
    for (int j = 0; j < 8; ++j) { u[j] += __shfl_xor(u[j], off, 64); w[j] += __shfl_xor(w[j], off, 64); }
  }
  if (lane == 0) {
    float m = -1e30f, tot = 0.f;
#pragma unroll
    for (int j = 0; j < 12; ++j) { s[j] += pa.gshB[j]; m = fmaxf(m, s[j]); }
#pragma unroll
    for (int j = 0; j < 12; ++j) { s[j] = __expf(s[j] - m); tot += s[j]; }
    float inv = 1.f / tot;
#pragma unroll
    for (int j = 0; j < 12; ++j) pa.gsh[(size_t)b * 12 + j] = s[j] * inv;
    m = -1e30f; tot = 0.f;
#pragma unroll
    for (int j = 0; j < 8; ++j) { u[j] += pa.g1B[j]; m = fmaxf(m, u[j]); }
#pragma unroll
    for (int j = 0; j < 8; ++j) { u[j] = __expf(u[j] - m); tot += u[j]; }
    inv = 1.f / tot;
#pragma unroll
    for (int j = 0; j < 8; ++j) pa.g1o[(size_t)b * 8 + j] = u[j] * inv;
    m = -1e30f; tot = 0.f;
#pragma unroll
    for (int j = 0; j < 8; ++j) { w[j] += pa.g2B[j]; m = fmaxf(m, w[j]); }
#pragma unroll
    for (int j = 0; j < 8; ++j) { w[j] = __expf(w[j] - m); tot += w[j]; }
    inv = 1.f / tot;
#pragma unroll
    for (int j = 0; j < 8; ++j) pa.g2o[(size_t)b * 8 + j] = w[j] * inv;
  }
}

// ---------- grouped GEMM: ring-3 LDS slots + counted vmcnt(3) (R9, unchanged) ----------
struct GemmDesc {
  const u16* A;
  const u16* BT;
  const float* bias;
  u16* C;
  int K;
  int N;
  int T;  // K/32
};
struct GemmArgs { GemmDesc d[12]; };

#define BARR __builtin_amdgcn_s_barrier()
#define WAITL0                                                   \
  {                                                              \
    asm volatile("s_waitcnt lgkmcnt(0)" ::: "memory");           \
    __builtin_amdgcn_sched_barrier(0);                           \
  }
#define WAITV(N)                                                 \
  {                                                              \
    asm volatile("s_waitcnt vmcnt(" #N ")" ::: "memory");        \
    __builtin_amdgcn_sched_barrier(0);                           \
  }

__global__ __launch_bounds__(512, 4) void k_gemm128(GemmArgs args) {
  __shared__ __align__(16) char lds[73728];
  u16* As = (u16*)lds;            // 3 x 128x32 = 24 KB
  u16* Bs = (u16*)(lds + 24576);  // 3 x 256x32 = 48 KB

  GemmDesc g = args.d[blockIdx.y];
  const int K = g.K, N = g.N, T = g.T;
  const int ntN = N >> 8;
  const int bx = blockIdx.x;
  const int nt = bx & (ntN - 1);
  const int bt = (ntN == 2) ? (bx >> 1) : bx;
  const int row0 = bt << 7;
  const int col0 = nt << 8;

  const int tid = threadIdx.x;
  const int lane = tid & 63;
  const int wid = tid >> 6;
  const int wm = wid & 1;
  const int wn = wid >> 1;
  const int lrow = lane & 15;
  const int lkq = lane >> 4;

  const int csw = (lkq ^ ((lrow >> 1) & 3)) * 16;
  int aoff[4], boff[4];
#pragma unroll
  for (int mi = 0; mi < 4; ++mi) aoff[mi] = (wm * 64 + mi * 16 + lrow) * 64 + csw;
#pragma unroll
  for (int ni = 0; ni < 4; ++ni) boff[ni] = (wn * 64 + ni * 16 + lrow) * 64 + csw;

  const int ar = tid >> 2;
  const int acs = (tid & 3) ^ ((ar >> 1) & 3);
  const u16* aSrc = g.A + (size_t)(row0 + ar) * K + acs * 8;
  const int br0 = tid >> 2;
  const int bc0 = (tid & 3) ^ ((br0 >> 1) & 3);
  const u16* bSrc0 = g.BT + (size_t)(col0 + br0) * K + bc0 * 8;
  const int br1 = 128 + (tid >> 2);
  const int bc1 = (tid & 3) ^ ((br1 >> 1) & 3);
  const u16* bSrc1 = g.BT + (size_t)(col0 + br1) * K + bc1 * 8;

  auto STAGE = [&](int s, int t) {
    GL2LDS16(aSrc + (size_t)t * 32, &As[s * 4096 + tid * 8]);
    GL2LDS16(bSrc0 + (size_t)t * 32, &Bs[s * 8192 + tid * 8]);
    GL2LDS16(bSrc1 + (size_t)t * 32, &Bs[s * 8192 + 4096 + tid * 8]);
  };

  f32x4 acc[4][4];
#pragma unroll
  for (int m = 0; m < 4; ++m)
#pragma unroll
    for (int n = 0; n < 4; ++n)
      acc[m][n] = (f32x4){0.f, 0.f, 0.f, 0.f};

  STAGE(0, 0);
  STAGE(1, 1);
  WAITV(3);
  BARR;

  int slot = 0, slot2 = 2;
  for (int t = 0; t < T; ++t) {
    const char* Ab = lds + slot * 8192;
    const char* Bb = lds + 24576 + slot * 16384;
    short8 a0, a1, b[4];
#pragma unroll
    for (int ni = 0; ni < 4; ++ni) b[ni] = *(const short8*)(Bb + boff[ni]);
    a0 = *(const short8*)(Ab + aoff[0]);
    a1 = *(const short8*)(Ab + aoff[1]);
    if (t + 2 < T) STAGE(slot2, t + 2);
    WAITL0;
    __builtin_amdgcn_s_setprio(1);
#pragma unroll
    for (int ni = 0; ni < 4; ++ni) {
      acc[0][ni] = __builtin_amdgcn_mfma_f32_16x16x32_bf16(a0, b[ni], acc[0][ni], 0, 0, 0);
      acc[1][ni] = __builtin_amdgcn_mfma_f32_16x16x32_bf16(a1, b[ni], acc[1][ni], 0, 0, 0);
    }
    __builtin_amdgcn_s_setprio(0);
    a0 = *(const short8*)(Ab + aoff[2]);
    a1 = *(const short8*)(Ab + aoff[3]);
    WAITL0;
    __builtin_amdgcn_s_setprio(1);
#pragma unroll
    for (int ni = 0; ni < 4; ++ni) {
      acc[2][ni] = __builtin_amdgcn_mfma_f32_16x16x32_bf16(a0, b[ni], acc[2][ni], 0, 0, 0);
      acc[3][ni] = __builtin_amdgcn_mfma_f32_16x16x32_bf16(a1, b[ni], acc[3][ni], 0, 0, 0);
    }
    __builtin_amdgcn_s_setprio(0);
    if (t + 2 < T) { WAITV(3); }
    else if (t + 1 < T) { WAITV(0); }
    BARR;
    slot = (slot == 2) ? 0 : slot + 1;
    slot2 = (slot2 == 2) ? 0 : slot2 + 1;
  }

#pragma unroll
  for (int ni = 0; ni < 4; ++ni) {
    const int gc = col0 + wn * 64 + ni * 16 + lrow;
    const float bv = g.bias[gc];
#pragma unroll
    for (int mi = 0; mi < 4; ++mi) {
      const int gr = row0 + wm * 64 + mi * 16 + lkq * 4;
#pragma unroll
      for (int j = 0; j < 4; ++j) {
        float o = fmaxf(acc[mi][ni][j] + bv, 0.f);
        g.C[(size_t)(gr + j) * N + gc] = f2bf(o);
      }
    }
  }
}

// ---------------- gated reduce: 3 outputs from 12 expert outputs ----------------
__global__ void k_reduce(const u16* __restrict__ OutB, const float* __restrict__ gsh,
                         const float* __restrict__ g1, const float* __restrict__ g2,
                         float* __restrict__ out) {
  int t = blockIdx.x * 256 + threadIdx.x;
  int b = t >> 5;
  int c0 = (t & 31) << 3;
  float wsh[12], w1[8], w2[8];
#pragma unroll
  for (int j = 0; j < 12; ++j) wsh[j] = gsh[(size_t)b * 12 + j];
#pragma unroll
  for (int j = 0; j < 8; ++j) { w1[j] = g1[(size_t)b * 8 + j]; w2[j] = g2[(size_t)b * 8 + j]; }
  float ash[8] = {0, 0, 0, 0, 0, 0, 0, 0};
  float a1[8] = {0, 0, 0, 0, 0, 0, 0, 0};
  float a2[8] = {0, 0, 0, 0, 0, 0, 0, 0};
#pragma unroll
  for (int e = 0; e < 12; ++e) {
    short8 v = *(const short8*)&OutB[((size_t)e * 4096 + b) * 256 + c0];
    float f[8];
#pragma unroll
    for (int i = 0; i < 8; ++i) f[i] = bf2f((u16)v[i]);
#pragma unroll
    for (int i = 0; i < 8; ++i) ash[i] += wsh[e] * f[i];
    if (e < 4) {
#pragma unroll
      for (int i = 0; i < 8; ++i) a1[i] += w1[e] * f[i];
    } else if (e < 8) {
#pragma unroll
      for (int i = 0; i < 8; ++i) a2[i] += w2[e - 4] * f[i];
    } else {
#pragma unroll
      for (int i = 0; i < 8; ++i) a1[i] += w1[e - 4] * f[i];
#pragma unroll
      for (int i = 0; i < 8; ++i) a2[i] += w2[e - 4] * f[i];
    }
  }
  size_t base = (size_t)b * 256 + c0;
  float4* o;
  o = (float4*)(out + base);
  o[0] = make_float4(ash[0], ash[1], ash[2], ash[3]);
  o[1] = make_float4(ash[4], ash[5], ash[6], ash[7]);
  o = (float4*)(out + 4096ull * 256 + base);
  o[0] = make_float4(a1[0], a1[1], a1[2], a1[3]);
  o[1] = make_float4(a1[4], a1[5], a1[6], a1[7]);
  o = (float4*)(out + 2ull * 4096 * 256 + base);
  o[0] = make_float4(a2[0], a2[1], a2[2], a2[3]);
  o[1] = make_float4(a2[4], a2[5], a2[6], a2[7]);
}

extern "C" void kernel_launch(void* const* d_in, const int* in_sizes, int n_in,
                              void* d_out, int out_size, void* d_ws, size_t ws_size,
                              hipStream_t stream) {
  const float* x_full = (const float*)d_in[0];
  const float* x_t1 = (const float*)d_in[1];
  const float* x_t2 = (const float*)d_in[2];
  const float* sh_W1 = (const float*)d_in[3];
  const float* sh_b1 = (const float*)d_in[4];
  const float* sh_W2 = (const float*)d_in[5];
  const float* sh_b2 = (const float*)d_in[6];
  const float* t1_W1 = (const float*)d_in[7];
  const float* t1_b1 = (const float*)d_in[8];
  const float* t1_W2 = (const float*)d_in[9];
  const float* t1_b2 = (const float*)d_in[10];
  const float* t2_W1 = (const float*)d_in[11];
  const float* t2_b1 = (const float*)d_in[12];
  const float* t2_W2 = (const float*)d_in[13];
  const float* t2_b2 = (const float*)d_in[14];
  const float* gsh_W = (const float*)d_in[15];
  const float* gsh_b = (const float*)d_in[16];
  const float* g1_W = (const float*)d_in[17];
  const float* g1_b = (const float*)d_in[18];
  const float* g2_W = (const float*)d_in[19];
  const float* g2_b = (const float*)d_in[20];

  char* ws = (char*)d_ws;
  size_t off = 0;
  auto alloc = [&](size_t bytes) -> void* {
    void* p = ws + off;
    off += (bytes + 255) & ~(size_t)255;
    return p;
  };
  u16* xf_b = (u16*)alloc(4096ull * 1024 * 2);
  u16* x1_b = (u16*)alloc(4096ull * 512 * 2);
  u16* x2_b = (u16*)alloc(4096ull * 512 * 2);
  u16* w1t_t1 = (u16*)alloc(4ull * 512 * 512 * 2);   // [e][HID=512][K=512]
  u16* w1t_t2 = (u16*)alloc(4ull * 512 * 512 * 2);
  u16* w1t_sh = (u16*)alloc(4ull * 512 * 1024 * 2);  // [e][512][1024]
  u16* w2t = (u16*)alloc(12ull * 256 * 512 * 2);     // [slot][OUT=256][HID=512]
  u16* H = (u16*)alloc(12ull * 4096 * 512 * 2);      // hidden [slot][4096][512]
  u16* OutB = (u16*)alloc(12ull * 4096 * 256 * 2);   // expert outputs [slot][4096][256]
  float* gshv = (float*)alloc(4096ull * 12 * 4);
  float* g1v = (float*)alloc(4096ull * 8 * 4);
  float* g2v = (float*)alloc(4096ull * 8 * 4);
  float* gshWT = (float*)alloc(12ull * 1024 * 4);    // transposed gate weights
  float* g1WT = (float*)alloc(8ull * 512 * 4);
  float* g2WT = (float*)alloc(8ull * 512 * 4);

  // --- gate-weight transpose (tiny) ---
  k_gateT<<<80, 256, 0, stream>>>(gsh_W, g1_W, g2_W, gshWT, g1WT, g2WT);

  // --- fused prep: gates/casts (blocks 0..1023) + weight transposes (1024..6655) ---
  PrepArgs pa;
  pa.d[0] = TD{t1_W1, w1t_t1, 8, 4, 512, 512, 0};
  pa.d[1] = TD{t2_W1, w1t_t2, 8, 4, 512, 512, 1024};
  pa.d[2] = TD{sh_W1, w1t_sh, 9, 4, 1024, 512, 2048};
  pa.d[3] = TD{t1_W2, w2t, 7, 3, 512, 256, 4096};
  pa.d[4] = TD{t2_W2, w2t + 4ull * 256 * 512, 7, 3, 512, 256, 4608};
  pa.d[5] = TD{sh_W2, w2t + 8ull * 256 * 512, 7, 3, 512, 256, 5120};
  pa.xf = x_full; pa.x1 = x_t1; pa.x2 = x_t2;
  pa.gshWT = gshWT; pa.gshB = gsh_b; pa.g1WT = g1WT; pa.g1B = g1_b;
  pa.g2WT = g2WT; pa.g2B = g2_b;
  pa.xfb = xf_b; pa.x1b = x1_b; pa.x2b = x2_b;
  pa.gsh = gshv; pa.g1o = g1v; pa.g2o = g2v;
  k_prep<<<6656, 256, 0, stream>>>(pa);

  // --- GEMM1: H = relu(x @ W1 + b1), grouped over 12 experts (shared K=1024 first) ---
  GemmArgs ga1;
  for (int e = 0; e < 4; ++e) {
    ga1.d[e] = GemmDesc{xf_b, w1t_sh + (size_t)e * 512 * 1024, sh_b1 + e * 512,
                        H + (size_t)(8 + e) * 4096 * 512, 1024, 512, 32};
    ga1.d[4 + e] = GemmDesc{x1_b, w1t_t1 + (size_t)e * 512 * 512, t1_b1 + e * 512,
                            H + (size_t)e * 4096 * 512, 512, 512, 16};
    ga1.d[8 + e] = GemmDesc{x2_b, w1t_t2 + (size_t)e * 512 * 512, t2_b1 + e * 512,
                            H + (size_t)(4 + e) * 4096 * 512, 512, 512, 16};
  }
  k_gemm128<<<dim3(64, 12), 512, 0, stream>>>(ga1);

  // --- GEMM2: Out = relu(H @ W2 + b2), grouped over 12 experts ---
  GemmArgs ga2;
  for (int e = 0; e < 12; ++e) {
    const float* bias = (e < 4) ? (t1_b2 + e * 256)
                      : (e < 8) ? (t2_b2 + (e - 4) * 256)
                                : (sh_b2 + (e - 8) * 256);
    ga2.d[e] = GemmDesc{H + (size_t)e * 4096 * 512, w2t + (size_t)e * 256 * 512, bias,
                        OutB + (size_t)e * 4096 * 256, 512, 256, 16};
  }
  k_gemm128<<<dim3(32, 12), 512, 0, stream>>>(ga2);

  // --- gated reduce -> d_out (out_sh | out1 | out2), fp32 ---
  k_reduce<<<512, 256, 0, stream>>>(OutB, gshv, g1v, g2v, (float*)d_out);
}

// Round 11
// 116.268 us; speedup vs baseline: 1.0431x; 1.0431x over previous
//
#include <hip/hip_runtime.h>

typedef unsigned short u16;
typedef __attribute__((ext_vector_type(8))) short short8;
typedef __attribute__((ext_vector_type(4))) float f32x4;

#define GL2LDS16(src, dst) __builtin_amdgcn_global_load_lds( \
    (const __attribute__((address_space(1))) void*)(src),    \
    (__attribute__((address_space(3))) void*)(dst), 16, 0, 0)

__device__ __forceinline__ u16 f2bf(float f) {
  union { float f; unsigned u; } v; v.f = f;
  unsigned r = v.u + 0x7fffu + ((v.u >> 16) & 1u);
  return (u16)(r >> 16);
}
__device__ __forceinline__ float bf2f(u16 h) {
  union { unsigned u; float f; } v; v.u = ((unsigned)h) << 16; return v.f;
}

// ---------------- gate-weight transpose: [K][J] fp32 -> [J][K] fp32 ----------------
__global__ void k_gateT(const float* __restrict__ gshW, const float* __restrict__ g1W,
                        const float* __restrict__ g2W, float* __restrict__ gshWT,
                        float* __restrict__ g1WT, float* __restrict__ g2WT) {
  int idx = blockIdx.x * 256 + threadIdx.x;
  if (idx < 12288) {
    int j = idx >> 10, k = idx & 1023;
    gshWT[j * 1024 + k] = gshW[k * 12 + j];
  } else if (idx < 16384) {
    int i2 = idx - 12288;
    int j = i2 >> 9, k = i2 & 511;
    g1WT[j * 512 + k] = g1W[k * 8 + j];
  } else if (idx < 20480) {
    int i2 = idx - 16384;
    int j = i2 >> 9, k = i2 & 511;
    g2WT[j * 512 + k] = g2W[k * 8 + j];
  }
}

// -------- gates (coalesced WT reads) + x->bf16 casts: 1 wave/row, 4 rows/block --------
__global__ void k_gates_cvt(const float* __restrict__ xf, const float* __restrict__ x1,
                            const float* __restrict__ x2,
                            const float* __restrict__ gshWT, const float* __restrict__ gshB,
                            const float* __restrict__ g1WT, const float* __restrict__ g1B,
                            const float* __restrict__ g2WT, const float* __restrict__ g2B,
                            u16* __restrict__ xfb, u16* __restrict__ x1b, u16* __restrict__ x2b,
                            float* __restrict__ gsh, float* __restrict__ g1o,
                            float* __restrict__ g2o) {
  const int b = blockIdx.x * 4 + (threadIdx.x >> 6);
  const int lane = threadIdx.x & 63;
  float s[12];
#pragma unroll
  for (int j = 0; j < 12; ++j) s[j] = 0.f;
  {
    const float4* x4 = (const float4*)(xf + (size_t)b * 1024);
    uint2* xw = (uint2*)(xfb + (size_t)b * 1024);
#pragma unroll
    for (int i = 0; i < 4; ++i) {
      const int kc = lane + 64 * i;
      float4 xv = x4[kc];
      uint2 pk;
      pk.x = (unsigned)f2bf(xv.x) | ((unsigned)f2bf(xv.y) << 16);
      pk.y = (unsigned)f2bf(xv.z) | ((unsigned)f2bf(xv.w) << 16);
      xw[kc] = pk;
#pragma unroll
      for (int j = 0; j < 12; ++j) {
        float4 wv = *(const float4*)(gshWT + j * 1024 + 4 * kc);
        s[j] += xv.x * wv.x + xv.y * wv.y + xv.z * wv.z + xv.w * wv.w;
      }
    }
  }
  float u[8], w[8];
#pragma unroll
  for (int j = 0; j < 8; ++j) { u[j] = 0.f; w[j] = 0.f; }
  {
    const float4* x41 = (const float4*)(x1 + (size_t)b * 512);
    const float4* x42 = (const float4*)(x2 + (size_t)b * 512);
    uint2* xw1 = (uint2*)(x1b + (size_t)b * 512);
    uint2* xw2 = (uint2*)(x2b + (size_t)b * 512);
#pragma unroll
    for (int i = 0; i < 2; ++i) {
      const int kc = lane + 64 * i;
      float4 v1 = x41[kc], v2 = x42[kc];
      uint2 p1, p2;
      p1.x = (unsigned)f2bf(v1.x) | ((unsigned)f2bf(v1.y) << 16);
      p1.y = (unsigned)f2bf(v1.z) | ((unsigned)f2bf(v1.w) << 16);
      p2.x = (unsigned)f2bf(v2.x) | ((unsigned)f2bf(v2.y) << 16);
      p2.y = (unsigned)f2bf(v2.z) | ((unsigned)f2bf(v2.w) << 16);
      xw1[kc] = p1; xw2[kc] = p2;
#pragma unroll
      for (int j = 0; j < 8; ++j) {
        float4 w1v = *(const float4*)(g1WT + j * 512 + 4 * kc);
        float4 w2v = *(const float4*)(g2WT + j * 512 + 4 * kc);
        u[j] += v1.x * w1v.x + v1.y * w1v.y + v1.z * w1v.z + v1.w * w1v.w;
        w[j] += v2.x * w2v.x + v2.y * w2v.y + v2.z * w2v.z + v2.w * w2v.w;
      }
    }
  }
#pragma unroll
  for (int off = 32; off >= 1; off >>= 1) {
#pragma unroll
    for (int j = 0; j < 12; ++j) s[j] += __shfl_xor(s[j], off, 64);
#pragma unroll
    for (int j = 0; j < 8; ++j) { u[j] += __shfl_xor(u[j], off, 64); w[j] += __shfl_xor(w[j], off, 64); }
  }
  if (lane == 0) {
    float m = -1e30f, tot = 0.f;
#pragma unroll
    for (int j = 0; j < 12; ++j) { s[j] += gshB[j]; m = fmaxf(m, s[j]); }
#pragma unroll
    for (int j = 0; j < 12; ++j) { s[j] = __expf(s[j] - m); tot += s[j]; }
    float inv = 1.f / tot;
#pragma unroll
    for (int j = 0; j < 12; ++j) gsh[(size_t)b * 12 + j] = s[j] * inv;
    m = -1e30f; tot = 0.f;
#pragma unroll
    for (int j = 0; j < 8; ++j) { u[j] += g1B[j]; m = fmaxf(m, u[j]); }
#pragma unroll
    for (int j = 0; j < 8; ++j) { u[j] = __expf(u[j] - m); tot += u[j]; }
    inv = 1.f / tot;
#pragma unroll
    for (int j = 0; j < 8; ++j) g1o[(size_t)b * 8 + j] = u[j] * inv;
    m = -1e30f; tot = 0.f;
#pragma unroll
    for (int j = 0; j < 8; ++j) { w[j] += g2B[j]; m = fmaxf(m, w[j]); }
#pragma unroll
    for (int j = 0; j < 8; ++j) { w[j] = __expf(w[j] - m); tot += w[j]; }
    inv = 1.f / tot;
#pragma unroll
    for (int j = 0; j < 8; ++j) g2o[(size_t)b * 8 + j] = w[j] * inv;
  }
}

// ------------- merged weight transpose+convert: fp32 [z][R][C] -> bf16 [z][C][R] -------------
struct TD { const float* src; u16* dst; int lgTps; int lgNtx; int R; int C; int tileBase; };
struct TArgs { TD d[6]; };

__global__ void k_transpose_all(TArgs ta) {
  __shared__ float tile[32][33];
  const int x = blockIdx.x;
  int di = 0;
#pragma unroll
  for (int i = 1; i < 6; ++i)
    if (x >= ta.d[i].tileBase) di = i;
  TD d = ta.d[di];
  const int local = x - d.tileBase;
  const int slice = local >> d.lgTps;
  const int ti = local & ((1 << d.lgTps) - 1);
  const int tx = ti & ((1 << d.lgNtx) - 1);
  const int ty = ti >> d.lgNtx;
  const float* src = d.src + (size_t)slice * d.R * d.C;
  u16* dst = d.dst + (size_t)slice * d.R * d.C;
  const int c0 = tx * 32, r0 = ty * 32;
  const int ttx = threadIdx.x, tty = threadIdx.y;
#pragma unroll
  for (int i = tty; i < 32; i += 8)
    tile[i][ttx] = src[(size_t)(r0 + i) * d.C + (c0 + ttx)];
  __syncthreads();
#pragma unroll
  for (int i = tty; i < 32; i += 8)
    dst[(size_t)(c0 + i) * d.R + (r0 + ttx)] = f2bf(tile[ttx][i]);
}

// ---------- grouped GEMM (R5 loop + proven swizzle), templated on BN ----------
// C = relu(A @ B^T + bias): A [4096][K] bf16, BT [N][K] bf16, C [4096][N] bf16.
// BM=128, BK=32, 8 waves (2M x NI*16-col strips), wave tile 64x(BN/4).
// BN=256: acc[4][4], 48KB LDS (GEMM1).  BN=128: acc[4][2], 32KB LDS (GEMM2,
// 768 blocks -> 3/CU queued, cross-block TLP hides the per-iter vmcnt0 drain).
// Swizzle (measured 0-conflict, R7/R8): 16B-chunk key=(row>>1)&3 both sides.
struct GemmDesc {
  const u16* A;
  const u16* BT;
  const float* bias;
  u16* C;
  int K;
  int N;
  int T;  // K/32
};
struct GemmArgs { GemmDesc d[12]; };

#define BARR __builtin_amdgcn_s_barrier()
#define WAITL0                                                   \
  {                                                              \
    asm volatile("s_waitcnt lgkmcnt(0)" ::: "memory");           \
    __builtin_amdgcn_sched_barrier(0);                           \
  }
#define WAITV0 asm volatile("s_waitcnt vmcnt(0)" ::: "memory")

template <int BN>
__global__ __launch_bounds__(512, 4) void k_gemm(GemmArgs args) {
  constexpr int NI = BN / 64;       // n-frags per wave
  __shared__ __align__(16) u16 As[2 * 128 * 32];
  __shared__ __align__(16) u16 Bs[2 * BN * 32];

  GemmDesc g = args.d[blockIdx.y];
  const int K = g.K, N = g.N, T = g.T;
  const int bx = blockIdx.x;
  const int nt = bx & 1;            // ntN == 2 for both GEMMs
  const int bt = bx >> 1;
  const int row0 = bt << 7;
  const int col0 = nt * BN;

  const int tid = threadIdx.x;
  const int lane = tid & 63;
  const int wid = tid >> 6;
  const int wm = wid & 1;           // 2 M-strips of 64
  const int wn = wid >> 1;          // 4 N-strips of BN/4
  const int lrow = lane & 15;
  const int lkq = lane >> 4;        // 0..3

  // ds_read offsets (row*64B + swizzled 16B chunk), key (row>>1)&3 = (lrow>>1)&3
  const int csw = (lkq ^ ((lrow >> 1) & 3)) * 16;
  int aoff[4], boff[NI];
#pragma unroll
  for (int mi = 0; mi < 4; ++mi) aoff[mi] = (wm * 64 + mi * 16 + lrow) * 64 + csw;
#pragma unroll
  for (int ni = 0; ni < NI; ++ni) boff[ni] = (wn * (BN / 4) + ni * 16 + lrow) * 64 + csw;

  // staging: linear LDS dest, pre-swizzled global src (same key)
  const int ar = tid >> 2;
  const int acs = (tid & 3) ^ ((ar >> 1) & 3);
  const u16* aSrc = g.A + (size_t)(row0 + ar) * K + acs * 8;
  const int br0 = tid >> 2;
  const int bc0 = (tid & 3) ^ ((br0 >> 1) & 3);
  const u16* bSrc0 = g.BT + (size_t)(col0 + br0) * K + bc0 * 8;
  const int br1 = 128 + (tid >> 2);
  const int bc1 = (tid & 3) ^ ((br1 >> 1) & 3);
  const u16* bSrc1 = g.BT + (size_t)(col0 + br1) * K + bc1 * 8;

  auto STAGE = [&](int buf, int t) {
    GL2LDS16(aSrc + (size_t)t * 32, &As[buf * 4096 + tid * 8]);
    GL2LDS16(bSrc0 + (size_t)t * 32, &Bs[buf * (BN * 32) + tid * 8]);
    if constexpr (BN == 256)
      GL2LDS16(bSrc1 + (size_t)t * 32, &Bs[buf * (BN * 32) + 4096 + tid * 8]);
  };

  f32x4 acc[4][NI];
#pragma unroll
  for (int m = 0; m < 4; ++m)
#pragma unroll
    for (int n = 0; n < NI; ++n)
      acc[m][n] = (f32x4){0.f, 0.f, 0.f, 0.f};

  STAGE(0, 0);
  WAITV0;
  BARR;

  for (int t = 0; t < T; ++t) {
    const int buf = t & 1;
    const char* Ab = (const char*)As + buf * 8192;
    const char* Bb = (const char*)Bs + buf * (BN * 64);
    short8 a0, a1, b[NI];
#pragma unroll
    for (int ni = 0; ni < NI; ++ni) b[ni] = *(const short8*)(Bb + boff[ni]);
    a0 = *(const short8*)(Ab + aoff[0]);
    a1 = *(const short8*)(Ab + aoff[1]);
    if (t + 1 < T) STAGE(buf ^ 1, t + 1);
    WAITL0;
    __builtin_amdgcn_s_setprio(1);
#pragma unroll
    for (int ni = 0; ni < NI; ++ni) {
      acc[0][ni] = __builtin_amdgcn_mfma_f32_16x16x32_bf16(a0, b[ni], acc[0][ni], 0, 0, 0);
      acc[1][ni] = __builtin_amdgcn_mfma_f32_16x16x32_bf16(a1, b[ni], acc[1][ni], 0, 0, 0);
    }
    __builtin_amdgcn_s_setprio(0);
    a0 = *(const short8*)(Ab + aoff[2]);
    a1 = *(const short8*)(Ab + aoff[3]);
    WAITL0;
    __builtin_amdgcn_s_setprio(1);
#pragma unroll
    for (int ni = 0; ni < NI; ++ni) {
      acc[2][ni] = __builtin_amdgcn_mfma_f32_16x16x32_bf16(a0, b[ni], acc[2][ni], 0, 0, 0);
      acc[3][ni] = __builtin_amdgcn_mfma_f32_16x16x32_bf16(a1, b[ni], acc[3][ni], 0, 0, 0);
    }
    __builtin_amdgcn_s_setprio(0);
    WAITV0;
    BARR;
  }

  // epilogue (R5's, measured fastest): C/D map col=lane&15, row=lkq*4+j
#pragma unroll
  for (int ni = 0; ni < NI; ++ni) {
    const int gc = col0 + wn * (BN / 4) + ni * 16 + lrow;
    const float bv = g.bias[gc];
#pragma unroll
    for (int mi = 0; mi < 4; ++mi) {
      const int gr = row0 + wm * 64 + mi * 16 + lkq * 4;
#pragma unroll
      for (int j = 0; j < 4; ++j) {
        float o = fmaxf(acc[mi][ni][j] + bv, 0.f);
        g.C[(size_t)(gr + j) * N + gc] = f2bf(o);
      }
    }
  }
}

// ---------------- gated reduce: 3 outputs from 12 expert outputs ----------------
__global__ void k_reduce(const u16* __restrict__ OutB, const float* __restrict__ gsh,
                         const float* __restrict__ g1, const float* __restrict__ g2,
                         float* __restrict__ out) {
  int t = blockIdx.x * 256 + threadIdx.x;
  int b = t >> 5;
  int c0 = (t & 31) << 3;
  float wsh[12], w1[8], w2[8];
#pragma unroll
  for (int j = 0; j < 12; ++j) wsh[j] = gsh[(size_t)b * 12 + j];
#pragma unroll
  for (int j = 0; j < 8; ++j) { w1[j] = g1[(size_t)b * 8 + j]; w2[j] = g2[(size_t)b * 8 + j]; }
  float ash[8] = {0, 0, 0, 0, 0, 0, 0, 0};
  float a1[8] = {0, 0, 0, 0, 0, 0, 0, 0};
  float a2[8] = {0, 0, 0, 0, 0, 0, 0, 0};
#pragma unroll
  for (int e = 0; e < 12; ++e) {
    short8 v = *(const short8*)&OutB[((size_t)e * 4096 + b) * 256 + c0];
    float f[8];
#pragma unroll
    for (int i = 0; i < 8; ++i) f[i] = bf2f((u16)v[i]);
#pragma unroll
    for (int i = 0; i < 8; ++i) ash[i] += wsh[e] * f[i];
    if (e < 4) {
#pragma unroll
      for (int i = 0; i < 8; ++i) a1[i] += w1[e] * f[i];
    } else if (e < 8) {
#pragma unroll
      for (int i = 0; i < 8; ++i) a2[i] += w2[e - 4] * f[i];
    } else {
#pragma unroll
      for (int i = 0; i < 8; ++i) a1[i] += w1[e - 4] * f[i];
#pragma unroll
      for (int i = 0; i < 8; ++i) a2[i] += w2[e - 4] * f[i];
    }
  }
  size_t base = (size_t)b * 256 + c0;
  float4* o;
  o = (float4*)(out + base);
  o[0] = make_float4(ash[0], ash[1], ash[2], ash[3]);
  o[1] = make_float4(ash[4], ash[5], ash[6], ash[7]);
  o = (float4*)(out + 4096ull * 256 + base);
  o[0] = make_float4(a1[0], a1[1], a1[2], a1[3]);
  o[1] = make_float4(a1[4], a1[5], a1[6], a1[7]);
  o = (float4*)(out + 2ull * 4096 * 256 + base);
  o[0] = make_float4(a2[0], a2[1], a2[2], a2[3]);
  o[1] = make_float4(a2[4], a2[5], a2[6], a2[7]);
}

extern "C" void kernel_launch(void* const* d_in, const int* in_sizes, int n_in,
                              void* d_out, int out_size, void* d_ws, size_t ws_size,
                              hipStream_t stream) {
  const float* x_full = (const float*)d_in[0];
  const float* x_t1 = (const float*)d_in[1];
  const float* x_t2 = (const float*)d_in[2];
  const float* sh_W1 = (const float*)d_in[3];
  const float* sh_b1 = (const float*)d_in[4];
  const float* sh_W2 = (const float*)d_in[5];
  const float* sh_b2 = (const float*)d_in[6];
  const float* t1_W1 = (const float*)d_in[7];
  const float* t1_b1 = (const float*)d_in[8];
  const float* t1_W2 = (const float*)d_in[9];
  const float* t1_b2 = (const float*)d_in[10];
  const float* t2_W1 = (const float*)d_in[11];
  const float* t2_b1 = (const float*)d_in[12];
  const float* t2_W2 = (const float*)d_in[13];
  const float* t2_b2 = (const float*)d_in[14];
  const float* gsh_W = (const float*)d_in[15];
  const float* gsh_b = (const float*)d_in[16];
  const float* g1_W = (const float*)d_in[17];
  const float* g1_b = (const float*)d_in[18];
  const float* g2_W = (const float*)d_in[19];
  const float* g2_b = (const float*)d_in[20];

  char* ws = (char*)d_ws;
  size_t off = 0;
  auto alloc = [&](size_t bytes) -> void* {
    void* p = ws + off;
    off += (bytes + 255) & ~(size_t)255;
    return p;
  };
  u16* xf_b = (u16*)alloc(4096ull * 1024 * 2);
  u16* x1_b = (u16*)alloc(4096ull * 512 * 2);
  u16* x2_b = (u16*)alloc(4096ull * 512 * 2);
  u16* w1t_t1 = (u16*)alloc(4ull * 512 * 512 * 2);   // [e][HID=512][K=512]
  u16* w1t_t2 = (u16*)alloc(4ull * 512 * 512 * 2);
  u16* w1t_sh = (u16*)alloc(4ull * 512 * 1024 * 2);  // [e][512][1024]
  u16* w2t = (u16*)alloc(12ull * 256 * 512 * 2);     // [slot][OUT=256][HID=512]
  u16* H = (u16*)alloc(12ull * 4096 * 512 * 2);      // hidden [slot][4096][512]
  u16* OutB = (u16*)alloc(12ull * 4096 * 256 * 2);   // expert outputs [slot][4096][256]
  float* gshv = (float*)alloc(4096ull * 12 * 4);
  float* g1v = (float*)alloc(4096ull * 8 * 4);
  float* g2v = (float*)alloc(4096ull * 8 * 4);
  float* gshWT = (float*)alloc(12ull * 1024 * 4);
  float* g1WT = (float*)alloc(8ull * 512 * 4);
  float* g2WT = (float*)alloc(8ull * 512 * 4);

  // --- gate-weight transpose (tiny) ---
  k_gateT<<<80, 256, 0, stream>>>(gsh_W, g1_W, g2_W, gshWT, g1WT, g2WT);

  // --- gates + x->bf16 (vectorized, coalesced WT reads) ---
  k_gates_cvt<<<1024, 256, 0, stream>>>(x_full, x_t1, x_t2, gshWT, gsh_b, g1WT, g1_b,
                                        g2WT, g2_b, xf_b, x1_b, x2_b, gshv, g1v, g2v);

  // --- weight transpose+convert, single launch ---
  TArgs ta;
  ta.d[0] = TD{t1_W1, w1t_t1, 8, 4, 512, 512, 0};
  ta.d[1] = TD{t2_W1, w1t_t2, 8, 4, 512, 512, 1024};
  ta.d[2] = TD{sh_W1, w1t_sh, 9, 4, 1024, 512, 2048};
  ta.d[3] = TD{t1_W2, w2t, 7, 3, 512, 256, 4096};
  ta.d[4] = TD{t2_W2, w2t + 4ull * 256 * 512, 7, 3, 512, 256, 4608};
  ta.d[5] = TD{sh_W2, w2t + 8ull * 256 * 512, 7, 3, 512, 256, 5120};
  k_transpose_all<<<5632, dim3(32, 8), 0, stream>>>(ta);

  // --- GEMM1 (BN=256): H = relu(x @ W1 + b1), shared K=1024 experts first ---
  GemmArgs ga1;
  for (int e = 0; e < 4; ++e) {
    ga1.d[e] = GemmDesc{xf_b, w1t_sh + (size_t)e * 512 * 1024, sh_b1 + e * 512,
                        H + (size_t)(8 + e) * 4096 * 512, 1024, 512, 32};
    ga1.d[4 + e] = GemmDesc{x1_b, w1t_t1 + (size_t)e * 512 * 512, t1_b1 + e * 512,
                            H + (size_t)e * 4096 * 512, 512, 512, 16};
    ga1.d[8 + e] = GemmDesc{x2_b, w1t_t2 + (size_t)e * 512 * 512, t2_b1 + e * 512,
                            H + (size_t)(4 + e) * 4096 * 512, 512, 512, 16};
  }
  k_gemm<256><<<dim3(64, 12), 512, 0, stream>>>(ga1);

  // --- GEMM2 (BN=128): Out = relu(H @ W2 + b2), 768 blocks for TLP ---
  GemmArgs ga2;
  for (int e = 0; e < 12; ++e) {
    const float* bias = (e < 4) ? (t1_b2 + e * 256)
                      : (e < 8) ? (t2_b2 + (e - 4) * 256)
                                : (sh_b2 + (e - 8) * 256);
    ga2.d[e] = GemmDesc{H + (size_t)e * 4096 * 512, w2t + (size_t)e * 256 * 512, bias,
                        OutB + (size_t)e * 4096 * 256, 512, 256, 16};
  }
  k_gemm<128><<<dim3(64, 12), 512, 0, stream>>>(ga2);

  // --- gated reduce -> d_out (out_sh | out1 | out2), fp32 ---
  k_reduce<<<512, 256, 0, stream>>>(OutB, gshv, g1v, g2v, (float*)d_out);
}

// Round 12
// 111.322 us; speedup vs baseline: 1.0894x; 1.0444x over previous
//
#include <hip/hip_runtime.h>

typedef unsigned short u16;
typedef __attribute__((ext_vector_type(8))) short short8;
typedef __attribute__((ext_vector_type(4))) float f32x4;

#define GL2LDS16(src, dst) __builtin_amdgcn_global_load_lds( \
    (const __attribute__((address_space(1))) void*)(src),    \
    (__attribute__((address_space(3))) void*)(dst), 16, 0, 0)

__device__ __forceinline__ u16 f2bf(float f) {
  union { float f; unsigned u; } v; v.f = f;
  unsigned r = v.u + 0x7fffu + ((v.u >> 16) & 1u);
  return (u16)(r >> 16);
}
__device__ __forceinline__ float bf2f(u16 h) {
  union { unsigned u; float f; } v; v.u = ((unsigned)h) << 16; return v.f;
}

// ------- merged: 6 weight transposes (blocks 0..5631) + gate-weight transpose (5632..5711) -------
struct TD { const float* src; u16* dst; int lgTps; int lgNtx; int R; int C; int tileBase; };
struct TArgs {
  TD d[6];
  const float *gshW, *g1W, *g2W;
  float *gshWT, *g1WT, *g2WT;
};

__global__ void k_transpose_all(TArgs ta) {
  __shared__ float tile[32][33];
  const int x = blockIdx.x;
  const int flat = threadIdx.y * 32 + threadIdx.x;
  if (x >= 5632) {
    // ---- gate-weight transpose: [K][J] fp32 -> [J][K] fp32 ----
    int idx = (x - 5632) * 256 + flat;
    if (idx < 12288) {
      int j = idx >> 10, k = idx & 1023;
      ta.gshWT[j * 1024 + k] = ta.gshW[k * 12 + j];
    } else if (idx < 16384) {
      int i2 = idx - 12288;
      int j = i2 >> 9, k = i2 & 511;
      ta.g1WT[j * 512 + k] = ta.g1W[k * 8 + j];
    } else if (idx < 20480) {
      int i2 = idx - 16384;
      int j = i2 >> 9, k = i2 & 511;
      ta.g2WT[j * 512 + k] = ta.g2W[k * 8 + j];
    }
    return;
  }
  int di = 0;
#pragma unroll
  for (int i = 1; i < 6; ++i)
    if (x >= ta.d[i].tileBase) di = i;
  TD d = ta.d[di];
  const int local = x - d.tileBase;
  const int slice = local >> d.lgTps;
  const int ti = local & ((1 << d.lgTps) - 1);
  const int tx = ti & ((1 << d.lgNtx) - 1);
  const int ty = ti >> d.lgNtx;
  const float* src = d.src + (size_t)slice * d.R * d.C;
  u16* dst = d.dst + (size_t)slice * d.R * d.C;
  const int c0 = tx * 32, r0 = ty * 32;
  const int ttx = threadIdx.x, tty = threadIdx.y;
#pragma unroll
  for (int i = tty; i < 32; i += 8)
    tile[i][ttx] = src[(size_t)(r0 + i) * d.C + (c0 + ttx)];
  __syncthreads();
#pragma unroll
  for (int i = tty; i < 32; i += 8)
    dst[(size_t)(c0 + i) * d.R + (r0 + ttx)] = f2bf(tile[ttx][i]);
}

// -------- gates (coalesced WT reads) + x->bf16 casts: 1 wave/row, 4 rows/block --------
__global__ void k_gates_cvt(const float* __restrict__ xf, const float* __restrict__ x1,
                            const float* __restrict__ x2,
                            const float* __restrict__ gshWT, const float* __restrict__ gshB,
                            const float* __restrict__ g1WT, const float* __restrict__ g1B,
                            const float* __restrict__ g2WT, const float* __restrict__ g2B,
                            u16* __restrict__ xfb, u16* __restrict__ x1b, u16* __restrict__ x2b,
                            float* __restrict__ gsh, float* __restrict__ g1o,
                            float* __restrict__ g2o) {
  const int b = blockIdx.x * 4 + (threadIdx.x >> 6);
  const int lane = threadIdx.x & 63;
  float s[12];
#pragma unroll
  for (int j = 0; j < 12; ++j) s[j] = 0.f;
  {
    const float4* x4 = (const float4*)(xf + (size_t)b * 1024);
    uint2* xw = (uint2*)(xfb + (size_t)b * 1024);
#pragma unroll
    for (int i = 0; i < 4; ++i) {
      const int kc = lane + 64 * i;
      float4 xv = x4[kc];
      uint2 pk;
      pk.x = (unsigned)f2bf(xv.x) | ((unsigned)f2bf(xv.y) << 16);
      pk.y = (unsigned)f2bf(xv.z) | ((unsigned)f2bf(xv.w) << 16);
      xw[kc] = pk;
#pragma unroll
      for (int j = 0; j < 12; ++j) {
        float4 wv = *(const float4*)(gshWT + j * 1024 + 4 * kc);
        s[j] += xv.x * wv.x + xv.y * wv.y + xv.z * wv.z + xv.w * wv.w;
      }
    }
  }
  float u[8], w[8];
#pragma unroll
  for (int j = 0; j < 8; ++j) { u[j] = 0.f; w[j] = 0.f; }
  {
    const float4* x41 = (const float4*)(x1 + (size_t)b * 512);
    const float4* x42 = (const float4*)(x2 + (size_t)b * 512);
    uint2* xw1 = (uint2*)(x1b + (size_t)b * 512);
    uint2* xw2 = (uint2*)(x2b + (size_t)b * 512);
#pragma unroll
    for (int i = 0; i < 2; ++i) {
      const int kc = lane + 64 * i;
      float4 v1 = x41[kc], v2 = x42[kc];
      uint2 p1, p2;
      p1.x = (unsigned)f2bf(v1.x) | ((unsigned)f2bf(v1.y) << 16);
      p1.y = (unsigned)f2bf(v1.z) | ((unsigned)f2bf(v1.w) << 16);
      p2.x = (unsigned)f2bf(v2.x) | ((unsigned)f2bf(v2.y) << 16);
      p2.y = (unsigned)f2bf(v2.z) | ((unsigned)f2bf(v2.w) << 16);
      xw1[kc] = p1; xw2[kc] = p2;
#pragma unroll
      for (int j = 0; j < 8; ++j) {
        float4 w1v = *(const float4*)(g1WT + j * 512 + 4 * kc);
        float4 w2v = *(const float4*)(g2WT + j * 512 + 4 * kc);
        u[j] += v1.x * w1v.x + v1.y * w1v.y + v1.z * w1v.z + v1.w * w1v.w;
        w[j] += v2.x * w2v.x + v2.y * w2v.y + v2.z * w2v.z + v2.w * w2v.w;
      }
    }
  }
#pragma unroll
  for (int off = 32; off >= 1; off >>= 1) {
#pragma unroll
    for (int j = 0; j < 12; ++j) s[j] += __shfl_xor(s[j], off, 64);
#pragma unroll
    for (int j = 0; j < 8; ++j) { u[j] += __shfl_xor(u[j], off, 64); w[j] += __shfl_xor(w[j], off, 64); }
  }
  if (lane == 0) {
    float m = -1e30f, tot = 0.f;
#pragma unroll
    for (int j = 0; j < 12; ++j) { s[j] += gshB[j]; m = fmaxf(m, s[j]); }
#pragma unroll
    for (int j = 0; j < 12; ++j) { s[j] = __expf(s[j] - m); tot += s[j]; }
    float inv = 1.f / tot;
#pragma unroll
    for (int j = 0; j < 12; ++j) gsh[(size_t)b * 12 + j] = s[j] * inv;
    m = -1e30f; tot = 0.f;
#pragma unroll
    for (int j = 0; j < 8; ++j) { u[j] += g1B[j]; m = fmaxf(m, u[j]); }
#pragma unroll
    for (int j = 0; j < 8; ++j) { u[j] = __expf(u[j] - m); tot += u[j]; }
    inv = 1.f / tot;
#pragma unroll
    for (int j = 0; j < 8; ++j) g1o[(size_t)b * 8 + j] = u[j] * inv;
    m = -1e30f; tot = 0.f;
#pragma unroll
    for (int j = 0; j < 8; ++j) { w[j] += g2B[j]; m = fmaxf(m, w[j]); }
#pragma unroll
    for (int j = 0; j < 8; ++j) { w[j] = __expf(w[j] - m); tot += w[j]; }
    inv = 1.f / tot;
#pragma unroll
    for (int j = 0; j < 8; ++j) g2o[(size_t)b * 8 + j] = w[j] * inv;
  }
}

// ---------- grouped GEMM (R5 loop + proven swizzle), templated on N-wave count ----------
// C = relu(A @ B^T + bias): A [4096][K] bf16, BT [N][K] bf16, C [4096][N] bf16.
// BM=128, BK=32; waves = 2M x NWN; wave tile 64x64 in BOTH variants.
// NWN=4: 512 thr, BN=256, 48KB LDS (GEMM1).  NWN=2: 256 thr, BN=128, 32KB LDS
// (GEMM2 - 4+ blocks/CU resident; cross-block TLP hides the per-tile vmcnt0 drain).
// Swizzle (measured 0-conflict, R7/R8): 16B-chunk key=(row>>1)&3 both sides.
struct GemmDesc {
  const u16* A;
  const u16* BT;
  const float* bias;
  u16* C;
  int K;
  int N;
  int T;  // K/32
};
struct GemmArgs { GemmDesc d[12]; };

#define BARR __builtin_amdgcn_s_barrier()
#define WAITL0                                                   \
  {                                                              \
    asm volatile("s_waitcnt lgkmcnt(0)" ::: "memory");           \
    __builtin_amdgcn_sched_barrier(0);                           \
  }
#define WAITV0 asm volatile("s_waitcnt vmcnt(0)" ::: "memory")

template <int NWN>
__global__ __launch_bounds__(NWN * 128, 4) void k_gemm(GemmArgs args) {
  constexpr int TPB = NWN * 128;     // threads per block
  constexpr int BN = NWN * 64;       // block N-tile
  constexpr int NA = 512 / TPB;      // A-stage iters (512 chunks of 16B)
  constexpr int NB = (BN * 4) / TPB; // B-stage iters
  __shared__ __align__(16) u16 As[2 * 128 * 32];
  __shared__ __align__(16) u16 Bs[2 * BN * 32];

  GemmDesc g = args.d[blockIdx.y];
  const int K = g.K, N = g.N, T = g.T;
  const int bx = blockIdx.x;
  const int nt = bx & 1;             // 2 N-tiles per expert in both GEMMs
  const int bt = bx >> 1;
  const int row0 = bt << 7;
  const int col0 = nt * BN;

  const int tid = threadIdx.x;
  const int lane = tid & 63;
  const int wid = tid >> 6;
  const int wm = wid & 1;            // 2 M-strips of 64
  const int wn = wid >> 1;           // NWN N-strips of 64
  const int lrow = lane & 15;
  const int lkq = lane >> 4;         // 0..3

  // ds_read offsets (row*64B + swizzled 16B chunk), key (row>>1)&3 = (lrow>>1)&3
  const int csw = (lkq ^ ((lrow >> 1) & 3)) * 16;
  int aoff[4], boff[4];
#pragma unroll
  for (int mi = 0; mi < 4; ++mi) aoff[mi] = (wm * 64 + mi * 16 + lrow) * 64 + csw;
#pragma unroll
  for (int ni = 0; ni < 4; ++ni) boff[ni] = (wn * 64 + ni * 16 + lrow) * 64 + csw;

  // staging: linear LDS dest, pre-swizzled global src (same key)
  const u16* aS[NA];
  const u16* bS[NB];
#pragma unroll
  for (int i = 0; i < NA; ++i) {
    const int c = i * TPB + tid;
    const int r = c >> 2;
    const int cs = (c & 3) ^ ((r >> 1) & 3);
    aS[i] = g.A + (size_t)(row0 + r) * K + cs * 8;
  }
#pragma unroll
  for (int i = 0; i < NB; ++i) {
    const int c = i * TPB + tid;
    const int r = c >> 2;
    const int cs = (c & 3) ^ ((r >> 1) & 3);
    bS[i] = g.BT + (size_t)(col0 + r) * K + cs * 8;
  }

  auto STAGE = [&](int buf, int t) {
#pragma unroll
    for (int i = 0; i < NA; ++i)
      GL2LDS16(aS[i] + (size_t)t * 32, &As[buf * 4096 + (i * TPB + tid) * 8]);
#pragma unroll
    for (int i = 0; i < NB; ++i)
      GL2LDS16(bS[i] + (size_t)t * 32, &Bs[buf * (BN * 32) + (i * TPB + tid) * 8]);
  };

  f32x4 acc[4][4];
#pragma unroll
  for (int m = 0; m < 4; ++m)
#pragma unroll
    for (int n = 0; n < 4; ++n)
      acc[m][n] = (f32x4){0.f, 0.f, 0.f, 0.f};

  STAGE(0, 0);
  WAITV0;
  BARR;

  for (int t = 0; t < T; ++t) {
    const int buf = t & 1;
    const char* Ab = (const char*)As + buf * 8192;
    const char* Bb = (const char*)Bs + buf * (BN * 64);
    short8 a0, a1, b[4];
#pragma unroll
    for (int ni = 0; ni < 4; ++ni) b[ni] = *(const short8*)(Bb + boff[ni]);
    a0 = *(const short8*)(Ab + aoff[0]);
    a1 = *(const short8*)(Ab + aoff[1]);
    if (t + 1 < T) STAGE(buf ^ 1, t + 1);
    WAITL0;
    __builtin_amdgcn_s_setprio(1);
#pragma unroll
    for (int ni = 0; ni < 4; ++ni) {
      acc[0][ni] = __builtin_amdgcn_mfma_f32_16x16x32_bf16(a0, b[ni], acc[0][ni], 0, 0, 0);
      acc[1][ni] = __builtin_amdgcn_mfma_f32_16x16x32_bf16(a1, b[ni], acc[1][ni], 0, 0, 0);
    }
    __builtin_amdgcn_s_setprio(0);
    a0 = *(const short8*)(Ab + aoff[2]);
    a1 = *(const short8*)(Ab + aoff[3]);
    WAITL0;
    __builtin_amdgcn_s_setprio(1);
#pragma unroll
    for (int ni = 0; ni < 4; ++ni) {
      acc[2][ni] = __builtin_amdgcn_mfma_f32_16x16x32_bf16(a0, b[ni], acc[2][ni], 0, 0, 0);
      acc[3][ni] = __builtin_amdgcn_mfma_f32_16x16x32_bf16(a1, b[ni], acc[3][ni], 0, 0, 0);
    }
    __builtin_amdgcn_s_setprio(0);
    WAITV0;
    BARR;
  }

  // epilogue (R5's, measured fastest): C/D map col=lane&15, row=lkq*4+j
#pragma unroll
  for (int ni = 0; ni < 4; ++ni) {
    const int gc = col0 + wn * 64 + ni * 16 + lrow;
    const float bv = g.bias[gc];
#pragma unroll
    for (int mi = 0; mi < 4; ++mi) {
      const int gr = row0 + wm * 64 + mi * 16 + lkq * 4;
#pragma unroll
      for (int j = 0; j < 4; ++j) {
        float o = fmaxf(acc[mi][ni][j] + bv, 0.f);
        g.C[(size_t)(gr + j) * N + gc] = f2bf(o);
      }
    }
  }
}

// ---------------- gated reduce: 3 outputs from 12 expert outputs ----------------
__global__ void k_reduce(const u16* __restrict__ OutB, const float* __restrict__ gsh,
                         const float* __restrict__ g1, const float* __restrict__ g2,
                         float* __restrict__ out) {
  int t = blockIdx.x * 256 + threadIdx.x;
  int b = t >> 5;
  int c0 = (t & 31) << 3;
  float wsh[12], w1[8], w2[8];
#pragma unroll
  for (int j = 0; j < 12; ++j) wsh[j] = gsh[(size_t)b * 12 + j];
#pragma unroll
  for (int j = 0; j < 8; ++j) { w1[j] = g1[(size_t)b * 8 + j]; w2[j] = g2[(size_t)b * 8 + j]; }
  float ash[8] = {0, 0, 0, 0, 0, 0, 0, 0};
  float a1[8] = {0, 0, 0, 0, 0, 0, 0, 0};
  float a2[8] = {0, 0, 0, 0, 0, 0, 0, 0};
#pragma unroll
  for (int e = 0; e < 12; ++e) {
    short8 v = *(const short8*)&OutB[((size_t)e * 4096 + b) * 256 + c0];
    float f[8];
#pragma unroll
    for (int i = 0; i < 8; ++i) f[i] = bf2f((u16)v[i]);
#pragma unroll
    for (int i = 0; i < 8; ++i) ash[i] += wsh[e] * f[i];
    if (e < 4) {
#pragma unroll
      for (int i = 0; i < 8; ++i) a1[i] += w1[e] * f[i];
    } else if (e < 8) {
#pragma unroll
      for (int i = 0; i < 8; ++i) a2[i] += w2[e - 4] * f[i];
    } else {
#pragma unroll
      for (int i = 0; i < 8; ++i) a1[i] += w1[e - 4] * f[i];
#pragma unroll
      for (int i = 0; i < 8; ++i) a2[i] += w2[e - 4] * f[i];
    }
  }
  size_t base = (size_t)b * 256 + c0;
  float4* o;
  o = (float4*)(out + base);
  o[0] = make_float4(ash[0], ash[1], ash[2], ash[3]);
  o[1] = make_float4(ash[4], ash[5], ash[6], ash[7]);
  o = (float4*)(out + 4096ull * 256 + base);
  o[0] = make_float4(a1[0], a1[1], a1[2], a1[3]);
  o[1] = make_float4(a1[4], a1[5], a1[6], a1[7]);
  o = (float4*)(out + 2ull * 4096 * 256 + base);
  o[0] = make_float4(a2[0], a2[1], a2[2], a2[3]);
  o[1] = make_float4(a2[4], a2[5], a2[6], a2[7]);
}

extern "C" void kernel_launch(void* const* d_in, const int* in_sizes, int n_in,
                              void* d_out, int out_size, void* d_ws, size_t ws_size,
                              hipStream_t stream) {
  const float* x_full = (const float*)d_in[0];
  const float* x_t1 = (const float*)d_in[1];
  const float* x_t2 = (const float*)d_in[2];
  const float* sh_W1 = (const float*)d_in[3];
  const float* sh_b1 = (const float*)d_in[4];
  const float* sh_W2 = (const float*)d_in[5];
  const float* sh_b2 = (const float*)d_in[6];
  const float* t1_W1 = (const float*)d_in[7];
  const float* t1_b1 = (const float*)d_in[8];
  const float* t1_W2 = (const float*)d_in[9];
  const float* t1_b2 = (const float*)d_in[10];
  const float* t2_W1 = (const float*)d_in[11];
  const float* t2_b1 = (const float*)d_in[12];
  const float* t2_W2 = (const float*)d_in[13];
  const float* t2_b2 = (const float*)d_in[14];
  const float* gsh_W = (const float*)d_in[15];
  const float* gsh_b = (const float*)d_in[16];
  const float* g1_W = (const float*)d_in[17];
  const float* g1_b = (const float*)d_in[18];
  const float* g2_W = (const float*)d_in[19];
  const float* g2_b = (const float*)d_in[20];

  char* ws = (char*)d_ws;
  size_t off = 0;
  auto alloc = [&](size_t bytes) -> void* {
    void* p = ws + off;
    off += (bytes + 255) & ~(size_t)255;
    return p;
  };
  u16* xf_b = (u16*)alloc(4096ull * 1024 * 2);
  u16* x1_b = (u16*)alloc(4096ull * 512 * 2);
  u16* x2_b = (u16*)alloc(4096ull * 512 * 2);
  u16* w1t_t1 = (u16*)alloc(4ull * 512 * 512 * 2);   // [e][HID=512][K=512]
  u16* w1t_t2 = (u16*)alloc(4ull * 512 * 512 * 2);
  u16* w1t_sh = (u16*)alloc(4ull * 512 * 1024 * 2);  // [e][512][1024]
  u16* w2t = (u16*)alloc(12ull * 256 * 512 * 2);     // [slot][OUT=256][HID=512]
  u16* H = (u16*)alloc(12ull * 4096 * 512 * 2);      // hidden [slot][4096][512]
  u16* OutB = (u16*)alloc(12ull * 4096 * 256 * 2);   // expert outputs [slot][4096][256]
  float* gshv = (float*)alloc(4096ull * 12 * 4);
  float* g1v = (float*)alloc(4096ull * 8 * 4);
  float* g2v = (float*)alloc(4096ull * 8 * 4);
  float* gshWT = (float*)alloc(12ull * 1024 * 4);
  float* g1WT = (float*)alloc(8ull * 512 * 4);
  float* g2WT = (float*)alloc(8ull * 512 * 4);

  // --- weight transposes + gate-weight transpose, single launch ---
  TArgs ta;
  ta.d[0] = TD{t1_W1, w1t_t1, 8, 4, 512, 512, 0};
  ta.d[1] = TD{t2_W1, w1t_t2, 8, 4, 512, 512, 1024};
  ta.d[2] = TD{sh_W1, w1t_sh, 9, 4, 1024, 512, 2048};
  ta.d[3] = TD{t1_W2, w2t, 7, 3, 512, 256, 4096};
  ta.d[4] = TD{t2_W2, w2t + 4ull * 256 * 512, 7, 3, 512, 256, 4608};
  ta.d[5] = TD{sh_W2, w2t + 8ull * 256 * 512, 7, 3, 512, 256, 5120};
  ta.gshW = gsh_W; ta.g1W = g1_W; ta.g2W = g2_W;
  ta.gshWT = gshWT; ta.g1WT = g1WT; ta.g2WT = g2WT;
  k_transpose_all<<<5712, dim3(32, 8), 0, stream>>>(ta);

  // --- gates + x->bf16 (vectorized, coalesced WT reads) ---
  k_gates_cvt<<<1024, 256, 0, stream>>>(x_full, x_t1, x_t2, gshWT, gsh_b, g1WT, g1_b,
                                        g2WT, g2_b, xf_b, x1_b, x2_b, gshv, g1v, g2v);

  // --- GEMM1 (8 waves, BN=256): H = relu(x @ W1 + b1), shared K=1024 experts first ---
  GemmArgs ga1;
  for (int e = 0; e < 4; ++e) {
    ga1.d[e] = GemmDesc{xf_b, w1t_sh + (size_t)e * 512 * 1024, sh_b1 + e * 512,
                        H + (size_t)(8 + e) * 4096 * 512, 1024, 512, 32};
    ga1.d[4 + e] = GemmDesc{x1_b, w1t_t1 + (size_t)e * 512 * 512, t1_b1 + e * 512,
                            H + (size_t)e * 4096 * 512, 512, 512, 16};
    ga1.d[8 + e] = GemmDesc{x2_b, w1t_t2 + (size_t)e * 512 * 512, t2_b1 + e * 512,
                            H + (size_t)(4 + e) * 4096 * 512, 512, 512, 16};
  }
  k_gemm<4><<<dim3(64, 12), 512, 0, stream>>>(ga1);

  // --- GEMM2 (4 waves, BN=128): Out = relu(H @ W2 + b2), 4+ blocks/CU for TLP ---
  GemmArgs ga2;
  for (int e = 0; e < 12; ++e) {
    const float* bias = (e < 4) ? (t1_b2 + e * 256)
                      : (e < 8) ? (t2_b2 + (e - 4) * 256)
                                : (sh_b2 + (e - 8) * 256);
    ga2.d[e] = GemmDesc{H + (size_t)e * 4096 * 512, w2t + (size_t)e * 256 * 512, bias,
                        OutB + (size_t)e * 4096 * 256, 512, 256, 16};
  }
  k_gemm<2><<<dim3(64, 12), 256, 0, stream>>>(ga2);

  // --- gated reduce -> d_out (out_sh | out1 | out2), fp32 ---
  k_reduce<<<512, 256, 0, stream>>>(OutB, gshv, g1v, g2v, (float*)d_out);
}